// Round 3
// baseline (658.588 us; speedup 1.0000x reference)
//
#include <hip/hip_runtime.h>

// VectorQuantizer: x [32768, 256] fp32, codebook [1024, 256] fp32.
// Reference (recomputed by harness in float32):
//   d[n,k] = fl( fl( ||x_n||^2 - 2*dot(x_n,c_k) ) + ||c_k||^2 )   (all fp32)
//   idx = argmin_k (first min), out = codebook[idx]
// We REPLICATE the fp32 arithmetic exactly:
//  - dot: single sequential fp32 FMA chain over d ascending (v_fmac_f32, no
//    reassociation at -O3). Staging round-trips are bit-exact fp32 copies.
//  - q = (S - 2*acc) + cn in fp32: two roundings (2*acc exact), left-to-right.
//  - S/cnorm: fp64 butterfly sums rounded once to fp32 (unchanged kernel).
//  - ties resolve to smallest k (strict <, ascending k; cross-lane reduce
//    breaks value-ties by smaller index).
//
// R2 post-mortem: the design was LDS-PIPE-BOUND, not latency-bound: 6
// ds_read_b128 (~12cy each, one LDS pipe/CU) per 32 FMA instrs (64 cy/SIMD)
// = 2-4.5x oversubscription -> 463 us ~= 4.3x the 109 us FMA floor. Also
// ~250 MB/dispatch scratch-spill writes (allocator capped ~88 VGPR).
// R3: scalar-operand GEMM. Wave owns 8 x-rows (wave-UNIFORM -> x flows
// through s_load_dwordx4 + the SGPR operand of v_fmac, zero vector-pipe
// cost). Lane owns one cb row per chunk (k=k0+lane) -> 1 ds_read_b128 per
// 32 FMA instrs = 0.75 LDS occupancy. LDS 66.8 KB -> 2 blocks/CU, 4
// waves/SIMD. Stride-260 (65*16B) rows: conflict-free b128 at immediate
// offsets (no per-iter address VALU).

#define D         256
#define K_TOTAL   1024
#define N_ROWS    32768
#define TN        64            // k per chunk = wavefront size; one k per lane
#define NCHUNK    (K_TOTAL / TN)
#define NTHREADS  512
#define WAVES     (NTHREADS / 64)
#define MI        8             // x-rows per wave (wave-uniform)
#define TM        (WAVES * MI)  // 64 rows per block -> 512 blocks = 2/CU exactly
#define CSTR      260           // cs row stride floats (1040 B = 65*16 B)

// ---------------- kernel 1: row norms for x and codebook ----------------
// Unchanged (bit-exact): fp32 squares -> fp64 left-assoc sum of 4 ->
// shfl_down butterfly 32..1 -> single fp64->fp32 rounding.
__global__ void norms_kernel(const float* __restrict__ x, const float* __restrict__ cb,
                             float* __restrict__ xnorm, float* __restrict__ cnorm) {
    const int wave = threadIdx.x >> 6;          // 0..3
    const int lane = threadIdx.x & 63;
    const int row0 = (blockIdx.x * 4 + wave) * 4;   // 4 rows per wave

    double s[4];
    #pragma unroll
    for (int r = 0; r < 4; ++r) {
        const int row = row0 + r;
        const float* src = (row < N_ROWS) ? (x + (size_t)row * D)
                                          : (cb + (size_t)(row - N_ROWS) * D);
        float4 v = *(const float4*)(src + lane * 4);
        float sx = v.x * v.x;
        float sy = v.y * v.y;
        float sz = v.z * v.z;
        float sw = v.w * v.w;
        s[r] = (double)sx + (double)sy + (double)sz + (double)sw;
    }
    #pragma unroll
    for (int off = 32; off > 0; off >>= 1) {
        #pragma unroll
        for (int r = 0; r < 4; ++r) s[r] += __shfl_down(s[r], off, 64);
    }
    if (lane == 0) {
        #pragma unroll
        for (int r = 0; r < 4; ++r) {
            const int row = row0 + r;
            if (row < N_ROWS) xnorm[row] = (float)s[r];
            else              cnorm[row - N_ROWS] = (float)s[r];
        }
    }
}

// ---------------- kernel 2: scalar-operand distance + argmin + gather ----------------
__global__ __launch_bounds__(NTHREADS, 4)
void vq_kernel(const float* __restrict__ x, const float* __restrict__ cb,
               const float* __restrict__ xnorm, const float* __restrict__ cnorm,
               float* __restrict__ out) {
    __shared__ float cs[TN * CSTR];          // 66560 B codebook chunk [64 k][256 d]
    __shared__ int   best[TM];               // 256 B  -> 66.8 KB total, 2 blocks/CU

    const int tid  = threadIdx.x;
    const int lane = tid & 63;
    const int wid  = __builtin_amdgcn_readfirstlane(tid >> 6);   // uniform wave id
    const int n0   = blockIdx.x * TM;
    const int wr0  = n0 + wid * MI;          // this wave's first x-row (uniform)

    // uniform pointer: all x accesses below have wave-uniform addresses ->
    // compiler emits s_load_dwordx4; values live in SGPRs and feed v_fmac's
    // single allowed scalar operand.
    const float* __restrict__ xw = x + (size_t)wr0 * D;

    // staging geometry: 64 rows x (8 float4-cols x 8 iters) per 512 threads
    const int trow = tid >> 3;               // 0..63  (cb row within chunk)
    const int tc4  = tid & 7;                // 0..7   (float4 column base)

    // wave-uniform row norms -> SGPRs
    float Sr[MI];
    #pragma unroll
    for (int r = 0; r < MI; ++r) Sr[r] = xnorm[wr0 + r];

    float runmin[MI];
    int   runidx[MI];
    #pragma unroll
    for (int r = 0; r < MI; ++r) { runmin[r] = 1e30f; runidx[r] = 0; }

    // ---- stage chunk 0 (coalesced 16B global, conflict-free LDS writes) ----
    {
        const float* src = cb + (size_t)trow * D + tc4 * 4;
        float* dst = cs + trow * CSTR + tc4 * 4;
        #pragma unroll
        for (int j = 0; j < 8; ++j) {
            float4 v = *(const float4*)(src + 32 * j);
            *(float4*)(dst + 32 * j) = v;
        }
    }
    __syncthreads();

    const float* bbase = cs + lane * CSTR;   // per-lane codebook row base

    for (int kc = 0; kc < NCHUNK; ++kc) {
        const int k0 = kc * TN;

        // T14: next chunk's global loads issued now, complete under the FMA
        // loop; ds_write after the read-barrier.
        float4 sreg[8];
        if (kc + 1 < NCHUNK) {
            const float* src = cb + (size_t)(k0 + TN + trow) * D + tc4 * 4;
            #pragma unroll
            for (int j = 0; j < 8; ++j) sreg[j] = *(const float4*)(src + 32 * j);
        }
        const float cn = cnorm[k0 + lane];   // per-lane, coalesced

        float acc[MI];
        #pragma unroll
        for (int r = 0; r < MI; ++r) acc[r] = 0.f;

        // ---- d-loop: 1 ds_read_b128 (imm offset) + 8 s_load_dwordx4 (imm
        // offset) + 32 v_fmac per 4-d group. Sequential fp32 chain per
        // (row, k), d ascending — DO NOT reorder. ----
        #pragma unroll 2
        for (int dd = 0; dd < D; dd += 4) {
            const float4 bv = *(const float4*)(bbase + dd);
            #pragma unroll
            for (int r = 0; r < MI; ++r) {
                const float4 av = *(const float4*)(xw + r * D + dd);  // uniform -> s_load
                acc[r] += av.x * bv.x;
                acc[r] += av.y * bv.y;
                acc[r] += av.z * bv.z;
                acc[r] += av.w * bv.w;
            }
        }

        // np-replica fp32 distance: q = (S - 2*acc) + cn, two roundings.
        const int k = k0 + lane;
        #pragma unroll
        for (int r = 0; r < MI; ++r) {
            const float t = Sr[r] - 2.0f * acc[r];   // one rounding (2*acc exact)
            const float q = t + cn;                  // second rounding
            if (q < runmin[r]) { runmin[r] = q; runidx[r] = k; }
        }

        __syncthreads();                     // all waves done reading cs
        if (kc + 1 < NCHUNK) {
            float* dst = cs + trow * CSTR + tc4 * 4;
            #pragma unroll
            for (int j = 0; j < 8; ++j) *(float4*)(dst + 32 * j) = sreg[j];
            __syncthreads();                 // cs ready for chunk kc+1
        }
    }

    // ---- wave-level argmin: 64 lanes hold disjoint k candidates ----
    // xor-butterfly; value tie -> smaller index (matches np.argmin first-hit).
    #pragma unroll
    for (int r = 0; r < MI; ++r) {
        float v = runmin[r];
        int  ix = runidx[r];
        #pragma unroll
        for (int off = 32; off > 0; off >>= 1) {
            const float ov = __shfl_xor(v, off, 64);
            const int   oi = __shfl_xor(ix, off, 64);
            if (ov < v || (ov == v && oi < ix)) { v = ov; ix = oi; }
        }
        if (lane == 0) best[wid * MI + r] = ix;
    }
    __syncthreads();

    // ---- gather winning codebook rows -> out, 16B coalesced ----
    {
        const int krow = best[trow];
        const float* src = cb + (size_t)krow * D + tc4 * 4;
        float* dst = out + (size_t)(n0 + trow) * D + tc4 * 4;
        #pragma unroll
        for (int j = 0; j < 8; ++j) {
            float4 v = *(const float4*)(src + 32 * j);
            *(float4*)(dst + 32 * j) = v;
        }
    }
}

extern "C" void kernel_launch(void* const* d_in, const int* in_sizes, int n_in,
                              void* d_out, int out_size, void* d_ws, size_t ws_size,
                              hipStream_t stream) {
    const float* x  = (const float*)d_in[0];   // [32768, 256]
    const float* cb = (const float*)d_in[1];   // [1024, 256]
    float* out = (float*)d_out;                // [32768, 256]

    // workspace: xnorm [32768 fp32] | cnorm [1024 fp32]  (132 KB)
    float* xnorm = (float*)d_ws;
    float* cnorm = xnorm + N_ROWS;

    norms_kernel<<<(N_ROWS + K_TOTAL) / 16, 256, 0, stream>>>(x, cb, xnorm, cnorm);
    vq_kernel<<<N_ROWS / TM, NTHREADS, 0, stream>>>(x, cb, xnorm, cnorm, out);
}